// Round 23
// baseline (157.365 us; speedup 1.0000x reference)
//
#include <hip/hip_runtime.h>
#include <hip/hip_bf16.h>
#include <stdint.h>

// Problem constants
#define M_B   1536      // 64*24 batch rows
#define N_L   500       // links
#define N_LP  512       // padded links (K of GEMM1, N of GEMM2)
#define N_P   20000     // paths
#define N_PP  20096     // padded paths (N of GEMM1 = 157*128, K of GEMM2)
#define N_G   4000      // OD groups
#define SPLITK 16
#define KCHUNK2 1280    // split-K chunk for GEMM2 (last = 896; both %32==0)
#define NQW   32        // group-slice split for softmax
#define GQW   (N_G / NQW)  // 125 groups per block
#define SVB   1024      // LDS staged bf16 per block (slice ~625+8sigma+GUNR < 1024)
#define GUNR  12        // unrolled group-walk length; P(size>12)~0.2% -> rare tail
#define NT1   (N_PP / 128)  // 157 n-tiles in GEMM1
#define MT1   (M_B / 128)   // 12 m-tiles
#define NB1   (NT1 * MT1)   // 1884 blocks

// Workspace layout (bytes). part (bf16, 25 MB) aliases vp (vp dead after softmax).
#define OFF_A1   ((size_t)0)                    // bf16 [1536][512]      1,572,864
#define OFF_D1   ((size_t)1572864)              // bf16 [512][20096]    20,578,304
#define OFF_DT   ((size_t)22151168)             // bf16 [20096][512]    20,578,304
#define OFF_VP   ((size_t)42729472)             // bf16 [1536][20096]   61,734,912
#define OFF_PART OFF_VP                         // bf16 [16][1536][512] 25,165,824 (aliases vp)
#define OFF_F    ((size_t)166199296)            // bf16 [1536][20096]   61,734,912
#define OFF_BND  ((size_t)227934208)            // int  [4001]

typedef __bf16 bf16x8 __attribute__((ext_vector_type(8)));
typedef __bf16 bf16x4 __attribute__((ext_vector_type(4)));
typedef float  f32x4  __attribute__((ext_vector_type(4)));
typedef int    i32x4  __attribute__((ext_vector_type(4)));

__device__ __forceinline__ void gload16(const void* g, void* l) {
  __builtin_amdgcn_global_load_lds(
      (const __attribute__((address_space(1))) void*)g,
      (__attribute__((address_space(3))) void*)l, 16, 0, 0);
}

// ---- prep: v_links -> bf16 A1 [1536][512], zero-padded ----
__global__ __launch_bounds__(256) void prep_a1(const float* __restrict__ X,
                                               const float* __restrict__ theta,
                                               const float* __restrict__ theta_links,
                                               __bf16* __restrict__ A1) {
  int idx = blockIdx.x * 256 + threadIdx.x;           // over 1536*512
  if (idx >= M_B * N_LP) return;
  int b = idx >> 9, l = idx & (N_LP - 1);
  float v = 0.f;
  if (l < N_L) {
    const float* x = X + ((size_t)b * N_L + l) * 5;
#pragma unroll
    for (int f = 0; f < 5; ++f) v += x[f] * fminf(theta[f], 0.f);
    v += theta_links[l];
  }
  A1[idx] = (__bf16)v;
}

// ---- prep: D -> bf16 D1 [512][20096] (row copy) AND Dt [20096][512] (transpose).
//      Vectorized (R22): float4 D loads, bf16x4 stores; LDS [32][133]. ----
__global__ __launch_bounds__(256) void prep_d(const float* __restrict__ D,
                                              __bf16* __restrict__ D1,
                                              __bf16* __restrict__ Dt) {
  __shared__ float t[32][133];
  const int pb = blockIdx.x * 128;   // path tile (157 tiles)
  const int lb = blockIdx.y * 32;    // link tile (16 tiles)
  const int tid = threadIdx.x;

#pragma unroll
  for (int it = 0; it < 4; ++it) {
    int fi = it * 256 + tid;
    int i = fi >> 5, q = fi & 31;
    int l = lb + i, p = pb + q * 4;
    f32x4 v = {};
    if (l < N_L) {
      if (p + 3 < N_P) {
        v = *(const f32x4*)&D[(size_t)l * N_P + p];
      } else {
#pragma unroll
        for (int k = 0; k < 4; ++k)
          v[k] = (p + k < N_P) ? D[(size_t)l * N_P + p + k] : 0.f;
      }
    }
    t[i][q * 4 + 0] = v[0];
    t[i][q * 4 + 1] = v[1];
    t[i][q * 4 + 2] = v[2];
    t[i][q * 4 + 3] = v[3];
    bf16x4 o;
#pragma unroll
    for (int k = 0; k < 4; ++k) o[k] = (__bf16)v[k];
    *(bf16x4*)&D1[(size_t)l * N_PP + p] = o;
  }
  __syncthreads();

#pragma unroll
  for (int it = 0; it < 4; ++it) {
    int fi = it * 256 + tid;
    int pl = fi >> 3, lq = fi & 7;
    int p = pb + pl, l = lb + lq * 4;
    bf16x4 o;
#pragma unroll
    for (int k = 0; k < 4; ++k) o[k] = (__bf16)t[lq * 4 + k][pl];
    *(bf16x4*)&Dt[(size_t)p * N_LP + l] = o;
  }
}

// ---- segment bounds: bounds[g] = first path index with seg >= g ----
__global__ __launch_bounds__(256) void seg_bounds(const int* __restrict__ seg,
                                                  int* __restrict__ bounds) {
  int g = blockIdx.x * 256 + threadIdx.x;
  if (g > N_G) return;
  int lo = 0, hi = N_P;
  while (lo < hi) { int mid = (lo + hi) >> 1; if (seg[mid] < g) lo = mid + 1; else hi = mid; }
  bounds[g] = lo;
}

// ---- GEMM (A and Bt row-major over K): C[m][n] = sum_k A[m][k]*Bt[n][k] ----
// 128x128 tile, 4 waves (2x2), BK=32, 2-phase double-buffer, (256,4) launch
// bounds (R20: reg cap 128 -> 4 blocks/CU was the win).
// MODE=1 (GEMM1): bijective XCD-chunked n-major map. MODE=2 (GEMM2): z-major.
// OBF=1: store C as bf16 (zstride in elems).
template <int MODE, int OBF>
__global__ __launch_bounds__(256, 4) void gemm_bt(const __bf16* __restrict__ A,
                                                  const __bf16* __restrict__ Bt,
                                                  void* __restrict__ C,
                                                  int lda, int ldb, int ldc,
                                                  int K, int kchunk, size_t zstride) {
  int bx, by, bz;
  if (MODE == 1) {
    int x = blockIdx.x & 7, k = blockIdx.x >> 3;
    int start = (x < 4) ? 236 * x : 944 + 235 * (x - 4);
    int L = start + k;
    bx = L / MT1;  by = L - bx * MT1;  bz = 0;
  } else {
    int bid = blockIdx.x; bz = bid & 15; bx = (bid >> 4) & 3; by = bid >> 6;
  }
  __shared__ __bf16 lsA[2][128 * 32];
  __shared__ __bf16 lsB[2][128 * 32];
  const int tid = threadIdx.x;
  const int lane = tid & 63;
  const int wv = tid >> 6;
  const int wr = wv >> 1, wc = wv & 1;
  const int m0 = by * 128;
  const int n0 = bx * 128;
  const int kb = bz * kchunk;
  const int klen = min(kchunk, K - kb);

  const int srow = wv * 16 + (lane >> 2);
  const int scol = 8 * ((lane & 3) ^ ((lane >> 4) & 3));   // inverse-swizzled source
  const int sb = (wv * 16) * 32;            // wave's staging base within a buffer
  const __bf16* gA = A + (size_t)(m0 + srow) * lda + kb + scol;
  const __bf16* gB = Bt + (size_t)(n0 + srow) * ldb + kb + scol;

  f32x4 acc[4][4] = {};
  const int fblk = 8 * (((lane >> 4) & 3) ^ ((lane >> 2) & 3));
  const int fra = (wr * 64 + (lane & 15)) * 32 + fblk;
  const int frb = (wc * 64 + (lane & 15)) * 32 + fblk;

#define STAGE(buf, kk)                                                        \
  {                                                                           \
    gload16(gA + (kk), &lsA[buf][sb]);                                        \
    gload16(gA + (size_t)64 * lda + (kk), &lsA[buf][64 * 32 + sb]);           \
    gload16(gB + (kk), &lsB[buf][sb]);                                        \
    gload16(gB + (size_t)64 * ldb + (kk), &lsB[buf][64 * 32 + sb]);           \
  }
#define COMPUTE(buf)                                                          \
  {                                                                           \
    bf16x8 av[4], bv[4];                                                      \
    _Pragma("unroll")                                                         \
    for (int r = 0; r < 4; ++r)                                               \
      av[r] = *(const bf16x8*)&lsA[buf][fra + r * 16 * 32];                   \
    _Pragma("unroll")                                                         \
    for (int c = 0; c < 4; ++c)                                               \
      bv[c] = *(const bf16x8*)&lsB[buf][frb + c * 16 * 32];                   \
    _Pragma("unroll")                                                         \
    for (int r = 0; r < 4; ++r)                                               \
      _Pragma("unroll")                                                       \
      for (int c = 0; c < 4; ++c)                                             \
        acc[r][c] = __builtin_amdgcn_mfma_f32_16x16x32_bf16(av[r], bv[c],     \
                                                            acc[r][c], 0, 0, 0); \
  }

  STAGE(0, 0);
  __syncthreads();
  int cur = 0;
  for (int kk = 32; kk < klen; kk += 32) {
    STAGE(cur ^ 1, kk);        // issue next-tile loads (hide under compute)
    COMPUTE(cur);
    __syncthreads();           // drain + barrier
    cur ^= 1;
  }
  COMPUTE(cur);                // final tile (no prefetch)
#undef STAGE
#undef COMPUTE

  const int erow = m0 + wr * 64 + (lane >> 4) * 4;
  const int ecol = n0 + wc * 64 + (lane & 15);
#pragma unroll
  for (int r = 0; r < 4; ++r)
#pragma unroll
    for (int c = 0; c < 4; ++c) {
      if (OBF) {
        __bf16* p = (__bf16*)C + (size_t)bz * zstride +
                    (size_t)(erow + r * 16) * ldc + (ecol + c * 16);
#pragma unroll
        for (int j = 0; j < 4; ++j) p[(size_t)j * ldc] = (__bf16)acc[r][c][j];
      } else {
        float* p = (float*)C + (size_t)bz * zstride +
                   (size_t)(erow + r * 16) * ldc + (ecol + c * 16);
#pragma unroll
        for (int j = 0; j < 4; ++j) p[(size_t)j * ldc] = acc[r][c][j];
      }
    }
}

// ---- grouped softmax: 1-wave blocks, registerized owner-lane groups. ----
// R23: contiguous unconditional 12-elem LDS read (1 address, immediate
// offsets — kills the per-j clamp/addr VALU chain), mask by VALUE:
// vm[j] = j<cnt ? v[j] : -inf for the max (m >= true max; softmax is
// shift-invariant so result is exact), exp masked to 0 by the same
// predicate (overflowed neighbor exps are replaced via select, no NaN).
__global__ __launch_bounds__(64) void seg_softmax(const __bf16* __restrict__ vp,
                                                  const int* __restrict__ bounds,
                                                  const float* __restrict__ q_sqrt,
                                                  __bf16* __restrict__ f) {
  __shared__ __bf16 svb[SVB];    // staged raw bf16 slice
  const int tid = threadIdx.x;
  const int b = blockIdx.x;
  const int g0 = blockIdx.y * GQW;

  const int s0 = bounds[g0];
  const int s0b = s0 & ~7;       // 16B-aligned element base
  const __bf16* row = vp + (size_t)b * N_PP;

  // async stage: 2 x (64 lanes x 16B) = 1024 bf16 (covers slice+GUNR overread)
  gload16(row + s0b + tid * 8, &svb[0]);
  gload16(row + s0b + 512 + tid * 8, &svb[512]);
  __syncthreads();               // vmcnt(0) + barrier

  __bf16* frow = f + (size_t)b * N_PP;

  // owner-lane groups: 2 rounds of 64
#pragma unroll
  for (int round = 0; round < 2; ++round) {
    int g = g0 + round * 64 + tid;
    if (g < g0 + GQW) {
      int s = bounds[g], e = bounds[g + 1];
      if (s < e) {
        int cnt = e - s;
        int base = s - s0b;
        // contiguous loads: one LDS address, immediate offsets
        float v[GUNR];
#pragma unroll
        for (int j = 0; j < GUNR; ++j) v[j] = (float)svb[base + j];
        // masked max (-inf beyond cnt); m >= true max, shift-invariant
        float m = v[0];
#pragma unroll
        for (int j = 1; j < GUNR; ++j)
          m = fmaxf(m, (j < cnt) ? v[j] : -3.4e38f);
        for (int p = s + GUNR; p < e; ++p) m = fmaxf(m, (float)svb[p - s0b]);  // rare tail
        // exp + denom, masked to 0 beyond cnt
        float ev[GUNR];
        float den = 0.f;
#pragma unroll
        for (int j = 0; j < GUNR; ++j) {
          float t = __expf(v[j] - m);
          t = (j < cnt) ? t : 0.f;
          ev[j] = t;
          den += t;
        }
        for (int p = s + GUNR; p < e; ++p) den += __expf((float)svb[p - s0b] - m);
        float qs = q_sqrt[g];
        float sc = qs * qs / den;
        // predicated stores at immediate offsets from frow+s
        __bf16* fp = frow + s;
#pragma unroll
        for (int j = 0; j < GUNR; ++j)
          if (j < cnt) fp[j] = (__bf16)(ev[j] * sc);
        for (int p = s + GUNR; p < e; ++p)
          frow[p] = (__bf16)(__expf((float)svb[p - s0b] - m) * sc);
      }
    }
  }
  // zero padded tail so GEMM2's K-padding contributes nothing
  if (blockIdx.y == NQW - 1)
    for (int p = N_P + tid; p < N_PP; p += 64) frow[p] = (__bf16)0.f;
}

// ---- reduce split-K bf16 partials -> out (l < 500; 500 = 125*4) ----
__global__ __launch_bounds__(256) void reduce_out(const __bf16* __restrict__ part,
                                                  float* __restrict__ out) {
  int idx = blockIdx.x * 256 + threadIdx.x;   // over 1536*125
  if (idx >= M_B * 125) return;
  int b = idx / 125, l4 = (idx - b * 125) * 4;
  f32x4 s = {};
#pragma unroll
  for (int z = 0; z < SPLITK; ++z) {
    bf16x4 v = *(const bf16x4*)&part[(size_t)z * M_B * N_LP + (size_t)b * N_LP + l4];
#pragma unroll
    for (int j = 0; j < 4; ++j) s[j] += (float)v[j];
  }
  *(f32x4*)&out[(size_t)b * N_L + l4] = s;
}

extern "C" void kernel_launch(void* const* d_in, const int* in_sizes, int n_in,
                              void* d_out, int out_size, void* d_ws, size_t ws_size,
                              hipStream_t stream) {
  const float* X           = (const float*)d_in[0];
  const float* theta       = (const float*)d_in[1];
  const float* theta_links = (const float*)d_in[2];
  const float* q_sqrt      = (const float*)d_in[3];
  const float* D           = (const float*)d_in[4];
  const int*   seg         = (const int*)d_in[5];
  float* out = (float*)d_out;

  char* ws = (char*)d_ws;
  __bf16* A1   = (__bf16*)(ws + OFF_A1);
  __bf16* D1   = (__bf16*)(ws + OFF_D1);
  __bf16* Dt   = (__bf16*)(ws + OFF_DT);
  __bf16* vp   = (__bf16*)(ws + OFF_VP);
  __bf16* part = (__bf16*)(ws + OFF_PART);
  __bf16* fbuf = (__bf16*)(ws + OFF_F);
  int*    bnd  = (int*)(ws + OFF_BND);

  prep_a1<<<(M_B * N_LP) / 256, 256, 0, stream>>>(X, theta, theta_links, A1);
  prep_d<<<dim3(NT1, 16), 256, 0, stream>>>(D, D1, Dt);
  seg_bounds<<<16, 256, 0, stream>>>(seg, bnd);

  // GEMM1 (XCD-chunked, bf16 out, 2-phase, 4-blocks/CU):
  // vp[b][p] = sum_l A1[b][l] * Dt[p][l]
  gemm_bt<1, 1><<<dim3(NB1, 1, 1), 256, 0, stream>>>(
      A1, Dt, vp, N_LP, N_LP, N_PP, N_LP, N_LP, (size_t)0);

  // softmax: 1-wave registerized owner-lane blocks, contiguous masked walk
  seg_softmax<<<dim3(M_B, NQW), 64, 0, stream>>>(vp, bnd, q_sqrt, fbuf);

  // GEMM2 (split-K, z-swizzled, 2-phase, 4-blocks/CU, bf16 partials):
  // part[z][b][l] = sum_{k in z} f[b][k]*D1[l][k]
  gemm_bt<2, 1><<<dim3((N_LP / 128) * (M_B / 128) * SPLITK, 1, 1), 256, 0, stream>>>(
      fbuf, D1, part, N_PP, N_PP, N_LP, N_PP, KCHUNK2, (size_t)(M_B * N_LP));

  reduce_out<<<(M_B * 125 + 255) / 256, 256, 0, stream>>>(part, out);
}

// Round 24
// 150.078 us; speedup vs baseline: 1.0486x; 1.0486x over previous
//
#include <hip/hip_runtime.h>
#include <hip/hip_bf16.h>
#include <stdint.h>

// Problem constants
#define M_B   1536      // 64*24 batch rows
#define N_L   500       // links
#define N_LP  512       // padded links (K of GEMM1, N of GEMM2)
#define N_P   20000     // paths
#define N_PP  20096     // padded paths (N of GEMM1 = 157*128, K of GEMM2)
#define N_G   4000      // OD groups
#define SPLITK 16
#define KCHUNK2 1280    // split-K chunk for GEMM2 (last = 896; both %32==0)
#define NQW   32        // group-slice split for softmax
#define GQW   (N_G / NQW)  // 125 groups per block
#define SVB   1024      // LDS staged bf16 per block (slice ~625+8sigma+GUNR < 1024)
#define GUNR  12        // unrolled group-walk length; P(size>12)~0.2% -> rare tail
#define NT1   (N_PP / 128)  // 157 n-tiles in GEMM1
#define MT1   (M_B / 128)   // 12 m-tiles
#define NB1   (NT1 * MT1)   // 1884 blocks

// Workspace layout (bytes). part (bf16, 25 MB) aliases vp (vp dead after softmax).
#define OFF_A1   ((size_t)0)                    // bf16 [1536][512]      1,572,864
#define OFF_D1   ((size_t)1572864)              // bf16 [512][20096]    20,578,304
#define OFF_DT   ((size_t)22151168)             // bf16 [20096][512]    20,578,304
#define OFF_VP   ((size_t)42729472)             // bf16 [1536][20096]   61,734,912
#define OFF_PART OFF_VP                         // bf16 [16][1536][512] 25,165,824 (aliases vp)
#define OFF_F    ((size_t)166199296)            // bf16 [1536][20096]   61,734,912
#define OFF_BND  ((size_t)227934208)            // int  [4001]

typedef __bf16 bf16x8 __attribute__((ext_vector_type(8)));
typedef __bf16 bf16x4 __attribute__((ext_vector_type(4)));
typedef float  f32x4  __attribute__((ext_vector_type(4)));
typedef int    i32x4  __attribute__((ext_vector_type(4)));

__device__ __forceinline__ void gload16(const void* g, void* l) {
  __builtin_amdgcn_global_load_lds(
      (const __attribute__((address_space(1))) void*)g,
      (__attribute__((address_space(3))) void*)l, 16, 0, 0);
}

// ---- prep: v_links -> bf16 A1 [1536][512], zero-padded ----
__global__ __launch_bounds__(256) void prep_a1(const float* __restrict__ X,
                                               const float* __restrict__ theta,
                                               const float* __restrict__ theta_links,
                                               __bf16* __restrict__ A1) {
  int idx = blockIdx.x * 256 + threadIdx.x;           // over 1536*512
  if (idx >= M_B * N_LP) return;
  int b = idx >> 9, l = idx & (N_LP - 1);
  float v = 0.f;
  if (l < N_L) {
    const float* x = X + ((size_t)b * N_L + l) * 5;
#pragma unroll
    for (int f = 0; f < 5; ++f) v += x[f] * fminf(theta[f], 0.f);
    v += theta_links[l];
  }
  A1[idx] = (__bf16)v;
}

// ---- prep: D -> bf16 D1 [512][20096] (row copy) AND Dt [20096][512] (transpose).
//      Vectorized (R22): float4 D loads, bf16x4 stores; LDS [32][133]. ----
__global__ __launch_bounds__(256) void prep_d(const float* __restrict__ D,
                                              __bf16* __restrict__ D1,
                                              __bf16* __restrict__ Dt) {
  __shared__ float t[32][133];
  const int pb = blockIdx.x * 128;   // path tile (157 tiles)
  const int lb = blockIdx.y * 32;    // link tile (16 tiles)
  const int tid = threadIdx.x;

#pragma unroll
  for (int it = 0; it < 4; ++it) {
    int fi = it * 256 + tid;
    int i = fi >> 5, q = fi & 31;
    int l = lb + i, p = pb + q * 4;
    f32x4 v = {};
    if (l < N_L) {
      if (p + 3 < N_P) {
        v = *(const f32x4*)&D[(size_t)l * N_P + p];
      } else {
#pragma unroll
        for (int k = 0; k < 4; ++k)
          v[k] = (p + k < N_P) ? D[(size_t)l * N_P + p + k] : 0.f;
      }
    }
    t[i][q * 4 + 0] = v[0];
    t[i][q * 4 + 1] = v[1];
    t[i][q * 4 + 2] = v[2];
    t[i][q * 4 + 3] = v[3];
    bf16x4 o;
#pragma unroll
    for (int k = 0; k < 4; ++k) o[k] = (__bf16)v[k];
    *(bf16x4*)&D1[(size_t)l * N_PP + p] = o;
  }
  __syncthreads();

#pragma unroll
  for (int it = 0; it < 4; ++it) {
    int fi = it * 256 + tid;
    int pl = fi >> 3, lq = fi & 7;
    int p = pb + pl, l = lb + lq * 4;
    bf16x4 o;
#pragma unroll
    for (int k = 0; k < 4; ++k) o[k] = (__bf16)t[lq * 4 + k][pl];
    *(bf16x4*)&Dt[(size_t)p * N_LP + l] = o;
  }
}

// ---- segment bounds: bounds[g] = first path index with seg >= g ----
__global__ __launch_bounds__(256) void seg_bounds(const int* __restrict__ seg,
                                                  int* __restrict__ bounds) {
  int g = blockIdx.x * 256 + threadIdx.x;
  if (g > N_G) return;
  int lo = 0, hi = N_P;
  while (lo < hi) { int mid = (lo + hi) >> 1; if (seg[mid] < g) lo = mid + 1; else hi = mid; }
  bounds[g] = lo;
}

// ---- GEMM (A and Bt row-major over K): C[m][n] = sum_k A[m][k]*Bt[n][k] ----
// 128x128 tile, 4 waves (2x2), BK=32, 2-phase double-buffer, (256,4) launch
// bounds (R20: reg cap 128 -> 4 blocks/CU was the win).
// MODE=1 (GEMM1): bijective XCD-chunked n-major map. MODE=2 (GEMM2): z-major.
// OBF=1: store C as bf16 (zstride in elems).
template <int MODE, int OBF>
__global__ __launch_bounds__(256, 4) void gemm_bt(const __bf16* __restrict__ A,
                                                  const __bf16* __restrict__ Bt,
                                                  void* __restrict__ C,
                                                  int lda, int ldb, int ldc,
                                                  int K, int kchunk, size_t zstride) {
  int bx, by, bz;
  if (MODE == 1) {
    int x = blockIdx.x & 7, k = blockIdx.x >> 3;
    int start = (x < 4) ? 236 * x : 944 + 235 * (x - 4);
    int L = start + k;
    bx = L / MT1;  by = L - bx * MT1;  bz = 0;
  } else {
    int bid = blockIdx.x; bz = bid & 15; bx = (bid >> 4) & 3; by = bid >> 6;
  }
  __shared__ __bf16 lsA[2][128 * 32];
  __shared__ __bf16 lsB[2][128 * 32];
  const int tid = threadIdx.x;
  const int lane = tid & 63;
  const int wv = tid >> 6;
  const int wr = wv >> 1, wc = wv & 1;
  const int m0 = by * 128;
  const int n0 = bx * 128;
  const int kb = bz * kchunk;
  const int klen = min(kchunk, K - kb);

  const int srow = wv * 16 + (lane >> 2);
  const int scol = 8 * ((lane & 3) ^ ((lane >> 4) & 3));   // inverse-swizzled source
  const int sb = (wv * 16) * 32;            // wave's staging base within a buffer
  const __bf16* gA = A + (size_t)(m0 + srow) * lda + kb + scol;
  const __bf16* gB = Bt + (size_t)(n0 + srow) * ldb + kb + scol;

  f32x4 acc[4][4] = {};
  const int fblk = 8 * (((lane >> 4) & 3) ^ ((lane >> 2) & 3));
  const int fra = (wr * 64 + (lane & 15)) * 32 + fblk;
  const int frb = (wc * 64 + (lane & 15)) * 32 + fblk;

#define STAGE(buf, kk)                                                        \
  {                                                                           \
    gload16(gA + (kk), &lsA[buf][sb]);                                        \
    gload16(gA + (size_t)64 * lda + (kk), &lsA[buf][64 * 32 + sb]);           \
    gload16(gB + (kk), &lsB[buf][sb]);                                        \
    gload16(gB + (size_t)64 * ldb + (kk), &lsB[buf][64 * 32 + sb]);           \
  }
#define COMPUTE(buf)                                                          \
  {                                                                           \
    bf16x8 av[4], bv[4];                                                      \
    _Pragma("unroll")                                                         \
    for (int r = 0; r < 4; ++r)                                               \
      av[r] = *(const bf16x8*)&lsA[buf][fra + r * 16 * 32];                   \
    _Pragma("unroll")                                                         \
    for (int c = 0; c < 4; ++c)                                               \
      bv[c] = *(const bf16x8*)&lsB[buf][frb + c * 16 * 32];                   \
    _Pragma("unroll")                                                         \
    for (int r = 0; r < 4; ++r)                                               \
      _Pragma("unroll")                                                       \
      for (int c = 0; c < 4; ++c)                                             \
        acc[r][c] = __builtin_amdgcn_mfma_f32_16x16x32_bf16(av[r], bv[c],     \
                                                            acc[r][c], 0, 0, 0); \
  }

  STAGE(0, 0);
  __syncthreads();
  int cur = 0;
  for (int kk = 32; kk < klen; kk += 32) {
    STAGE(cur ^ 1, kk);        // issue next-tile loads (hide under compute)
    COMPUTE(cur);
    __syncthreads();           // drain + barrier
    cur ^= 1;
  }
  COMPUTE(cur);                // final tile (no prefetch)
#undef STAGE
#undef COMPUTE

  const int erow = m0 + wr * 64 + (lane >> 4) * 4;
  const int ecol = n0 + wc * 64 + (lane & 15);
#pragma unroll
  for (int r = 0; r < 4; ++r)
#pragma unroll
    for (int c = 0; c < 4; ++c) {
      if (OBF) {
        __bf16* p = (__bf16*)C + (size_t)bz * zstride +
                    (size_t)(erow + r * 16) * ldc + (ecol + c * 16);
#pragma unroll
        for (int j = 0; j < 4; ++j) p[(size_t)j * ldc] = (__bf16)acc[r][c][j];
      } else {
        float* p = (float*)C + (size_t)bz * zstride +
                   (size_t)(erow + r * 16) * ldc + (ecol + c * 16);
#pragma unroll
        for (int j = 0; j < 4; ++j) p[(size_t)j * ldc] = acc[r][c][j];
      }
    }
}

// ---- grouped softmax: 1-wave blocks, registerized owner-lane groups. ----
// R24: results written back into svb (cheap predicated ds_write_b16 at
// immediate offsets, disjoint group regions), then one COALESCED bf16x8
// sweep of [s0,e0) to f. Replaces 24 scattered 2-byte global stores/wave
// (R23 profile: VALUBusy 46%, occ 71%, neither pipe saturated -> store
// address-divergence stall). Values bit-identical (same bf16 rounding).
__global__ __launch_bounds__(64) void seg_softmax(const __bf16* __restrict__ vp,
                                                  const int* __restrict__ bounds,
                                                  const float* __restrict__ q_sqrt,
                                                  __bf16* __restrict__ f) {
  __shared__ __bf16 svb[SVB];    // staged raw bf16 slice; overwritten with results
  const int tid = threadIdx.x;
  const int b = blockIdx.x;
  const int g0 = blockIdx.y * GQW;

  const int s0 = bounds[g0];
  const int e0 = (blockIdx.y == NQW - 1) ? N_P : bounds[g0 + GQW];
  const int s0b = s0 & ~7;       // 16B-aligned element base
  const __bf16* row = vp + (size_t)b * N_PP;

  // async stage: 2 x (64 lanes x 16B) = 1024 bf16 (covers slice+GUNR overread)
  gload16(row + s0b + tid * 8, &svb[0]);
  gload16(row + s0b + 512 + tid * 8, &svb[512]);
  __syncthreads();               // vmcnt(0) + barrier

  __bf16* frow = f + (size_t)b * N_PP;

  // owner-lane groups: 2 rounds of 64; results -> svb in place
#pragma unroll
  for (int round = 0; round < 2; ++round) {
    int g = g0 + round * 64 + tid;
    if (g < g0 + GQW) {
      int s = bounds[g], e = bounds[g + 1];
      if (s < e) {
        int cnt = e - s;
        int base = s - s0b;
        // contiguous loads: one LDS address, immediate offsets
        float v[GUNR];
#pragma unroll
        for (int j = 0; j < GUNR; ++j) v[j] = (float)svb[base + j];
        // masked max (-inf beyond cnt); m >= true max, shift-invariant
        float m = v[0];
#pragma unroll
        for (int j = 1; j < GUNR; ++j)
          m = fmaxf(m, (j < cnt) ? v[j] : -3.4e38f);
        for (int p = s + GUNR; p < e; ++p) m = fmaxf(m, (float)svb[p - s0b]);  // rare tail
        // exp + denom, masked to 0 beyond cnt
        float ev[GUNR];
        float den = 0.f;
#pragma unroll
        for (int j = 0; j < GUNR; ++j) {
          float t = __expf(v[j] - m);
          t = (j < cnt) ? t : 0.f;
          ev[j] = t;
          den += t;
        }
        float tail = 0.f;
        for (int p = s + GUNR; p < e; ++p) tail += __expf((float)svb[p - s0b] - m);
        den += tail;
        float qs = q_sqrt[g];
        float sc = qs * qs / den;
        // write results back to LDS (disjoint per group; immediate offsets)
        for (int p = s + GUNR; p < e; ++p)
          svb[p - s0b] = (__bf16)(__expf((float)svb[p - s0b] - m) * sc);
#pragma unroll
        for (int j = 0; j < GUNR; ++j)
          if (j < cnt) svb[base + j] = (__bf16)(ev[j] * sc);
      }
    }
  }
  __syncthreads();

  // coalesced sweep [s0, e0) -> frow: scalar head to 8-align, bf16x8 middle, tail
  const int sA = (s0 + 7) & ~7;
  const int eA = (e0 > sA) ? (e0 & ~7) : sA;
  for (int p = s0 + tid; p < ((sA < e0) ? sA : e0); p += 64)
    frow[p] = svb[p - s0b];
  for (int i = tid; sA + i * 8 < eA; i += 64)
    *(bf16x8*)&frow[sA + i * 8] = *(const bf16x8*)&svb[sA - s0b + i * 8];
  for (int p = ((eA > s0) ? eA : s0) + tid; p < e0; p += 64)
    frow[p] = svb[p - s0b];

  // zero padded tail so GEMM2's K-padding contributes nothing
  if (blockIdx.y == NQW - 1)
    for (int p = N_P + tid; p < N_PP; p += 64) frow[p] = (__bf16)0.f;
}

// ---- reduce split-K bf16 partials -> out (l < 500; 500 = 125*4) ----
__global__ __launch_bounds__(256) void reduce_out(const __bf16* __restrict__ part,
                                                  float* __restrict__ out) {
  int idx = blockIdx.x * 256 + threadIdx.x;   // over 1536*125
  if (idx >= M_B * 125) return;
  int b = idx / 125, l4 = (idx - b * 125) * 4;
  f32x4 s = {};
#pragma unroll
  for (int z = 0; z < SPLITK; ++z) {
    bf16x4 v = *(const bf16x4*)&part[(size_t)z * M_B * N_LP + (size_t)b * N_LP + l4];
#pragma unroll
    for (int j = 0; j < 4; ++j) s[j] += (float)v[j];
  }
  *(f32x4*)&out[(size_t)b * N_L + l4] = s;
}

extern "C" void kernel_launch(void* const* d_in, const int* in_sizes, int n_in,
                              void* d_out, int out_size, void* d_ws, size_t ws_size,
                              hipStream_t stream) {
  const float* X           = (const float*)d_in[0];
  const float* theta       = (const float*)d_in[1];
  const float* theta_links = (const float*)d_in[2];
  const float* q_sqrt      = (const float*)d_in[3];
  const float* D           = (const float*)d_in[4];
  const int*   seg         = (const int*)d_in[5];
  float* out = (float*)d_out;

  char* ws = (char*)d_ws;
  __bf16* A1   = (__bf16*)(ws + OFF_A1);
  __bf16* D1   = (__bf16*)(ws + OFF_D1);
  __bf16* Dt   = (__bf16*)(ws + OFF_DT);
  __bf16* vp   = (__bf16*)(ws + OFF_VP);
  __bf16* part = (__bf16*)(ws + OFF_PART);
  __bf16* fbuf = (__bf16*)(ws + OFF_F);
  int*    bnd  = (int*)(ws + OFF_BND);

  prep_a1<<<(M_B * N_LP) / 256, 256, 0, stream>>>(X, theta, theta_links, A1);
  prep_d<<<dim3(NT1, 16), 256, 0, stream>>>(D, D1, Dt);
  seg_bounds<<<16, 256, 0, stream>>>(seg, bnd);

  // GEMM1 (XCD-chunked, bf16 out, 2-phase, 4-blocks/CU):
  // vp[b][p] = sum_l A1[b][l] * Dt[p][l]
  gemm_bt<1, 1><<<dim3(NB1, 1, 1), 256, 0, stream>>>(
      A1, Dt, vp, N_LP, N_LP, N_PP, N_LP, N_LP, (size_t)0);

  // softmax: 1-wave owner-lane blocks, LDS write-back + coalesced sweep
  seg_softmax<<<dim3(M_B, NQW), 64, 0, stream>>>(vp, bnd, q_sqrt, fbuf);

  // GEMM2 (split-K, z-swizzled, 2-phase, 4-blocks/CU, bf16 partials):
  // part[z][b][l] = sum_{k in z} f[b][k]*D1[l][k]
  gemm_bt<2, 1><<<dim3((N_LP / 128) * (M_B / 128) * SPLITK, 1, 1), 256, 0, stream>>>(
      fbuf, D1, part, N_PP, N_PP, N_LP, N_PP, KCHUNK2, (size_t)(M_B * N_LP));

  reduce_out<<<(M_B * 125 + 255) / 256, 256, 0, stream>>>(part, out);
}